// Round 3
// baseline (160.168 us; speedup 1.0000x reference)
//
#include <hip/hip_runtime.h>

#define BB 16
#define NN 1024
#define LALPHA 0.2f
#define MAXD 192

// ---------------- CSR build from dense adjacency ----------------
__global__ void build_csr(const float* __restrict__ adj, int* __restrict__ deg,
                          int* __restrict__ cols) {
    __shared__ int cnt;
    int i = blockIdx.x;
    if (threadIdx.x == 0) cnt = 0;
    __syncthreads();
    for (int j = threadIdx.x; j < NN; j += blockDim.x) {
        if (adj[(size_t)i * NN + j] > 0.0f) {
            int p = atomicAdd(&cnt, 1);
            if (p < MAXD) cols[(size_t)i * MAXD + p] = j;
        }
    }
    __syncthreads();
    if (threadIdx.x == 0) deg[i] = cnt < MAXD ? cnt : MAXD;
}

// ---------------- fused GEMM + attention-score epilogue ----------------
template <int FOUT, int RB>
__global__ void gemm_score(const float* __restrict__ A0, const float* __restrict__ A1,
                           const float* __restrict__ W, const float* __restrict__ avec,
                           float* __restrict__ h, float* __restrict__ s_src,
                           float* __restrict__ s_dst) {
    constexpr int TFN = FOUT / 4;
    constexpr int NT = (RB / 4) * TFN;
    __shared__ float xs[RB][132];
    int t = threadIdx.x;
    int tf = t % TFN, tr = t / TFN;
    int f0 = tf * 4, r0 = tr * 4;
    int base = blockIdx.x * RB;

    for (int idx = t; idx < RB * 32; idx += NT) {
        int r = idx >> 5, c = (idx & 31) * 4;
        float4 v = (c < 64) ? *(const float4*)(A0 + (size_t)(base + r) * 64 + c)
                            : *(const float4*)(A1 + (size_t)(base + r) * 64 + (c - 64));
        xs[r][c] = v.x; xs[r][c + 1] = v.y; xs[r][c + 2] = v.z; xs[r][c + 3] = v.w;
    }
    __syncthreads();

    float acc[4][4] = {};
    for (int k = 0; k < 128; k += 4) {
        float4 xv[4], wv[4];
#pragma unroll
        for (int i = 0; i < 4; i++) xv[i] = *(const float4*)&xs[r0 + i][k];
#pragma unroll
        for (int i = 0; i < 4; i++) wv[i] = *(const float4*)(W + (size_t)(k + i) * FOUT + f0);
#pragma unroll
        for (int i = 0; i < 4; i++) {
            float xr[4] = {xv[i].x, xv[i].y, xv[i].z, xv[i].w};
#pragma unroll
            for (int kk = 0; kk < 4; kk++) {
                acc[i][0] += xr[kk] * wv[kk].x;
                acc[i][1] += xr[kk] * wv[kk].y;
                acc[i][2] += xr[kk] * wv[kk].z;
                acc[i][3] += xr[kk] * wv[kk].w;
            }
        }
    }

    float a_s[4], a_d[4];
#pragma unroll
    for (int i = 0; i < 4; i++) {
        a_s[i] = avec[f0 + i];
        a_d[i] = avec[FOUT + f0 + i];
    }
#pragma unroll
    for (int i = 0; i < 4; i++) {
        int m = base + r0 + i;
        *(float4*)(h + (size_t)m * FOUT + f0) =
            make_float4(acc[i][0], acc[i][1], acc[i][2], acc[i][3]);
        float ps = acc[i][0] * a_s[0] + acc[i][1] * a_s[1] + acc[i][2] * a_s[2] + acc[i][3] * a_s[3];
        float pd = acc[i][0] * a_d[0] + acc[i][1] * a_d[1] + acc[i][2] * a_d[2] + acc[i][3] * a_d[3];
#pragma unroll
        for (int o = TFN / 2; o >= 1; o >>= 1) {
            ps += __shfl_xor(ps, o);
            pd += __shfl_xor(pd, o);
        }
        if (tf == 0) {
            s_src[m] = ps;
            s_dst[m] = pd;
        }
    }
}

// ---------------- attention layer 1 (F=128), 2 waves/node feature-split ----------------
// Block: 256 thr = 4 waves = 2 nodes. No __syncthreads (redundant softmax per wave).
__global__ __launch_bounds__(256) void attn1_kernel(
    const int* __restrict__ deg, const int* __restrict__ cols,
    const float* __restrict__ h1, const float* __restrict__ s_src,
    const float* __restrict__ s_dst, const float* __restrict__ state,
    float* __restrict__ rstate, float* __restrict__ zbuf) {
    int wv = threadIdx.x >> 6;
    int lane = threadIdx.x & 63;
    int node = wv >> 1;
    int half = wv & 1;
    int bi = blockIdx.x * 2 + node;
    int i = bi & (NN - 1);
    int b = bi >> 10;
    int d = deg[i];
    float ssrc = s_src[bi];
    __shared__ float w[2][MAXD];
    __shared__ int cl[2][MAXD];

    // e-scores in registers (each wave covers all j redundantly)
    float ev[3];
    float mx = -1e30f;
    int nslot = 0;
    for (int j = lane; j < d; j += 64, nslot++) {
        int c = cols[(size_t)i * MAXD + j];
        cl[node][j] = c;
        float e = ssrc + s_dst[b * NN + c];
        e = e > 0.f ? e : LALPHA * e;
        ev[nslot] = e;
        mx = fmaxf(mx, e);
    }
#pragma unroll
    for (int o = 32; o >= 1; o >>= 1) mx = fmaxf(mx, __shfl_xor(mx, o));
    float sum = 0.f;
    {
        int s = 0;
        for (int j = lane; j < d; j += 64, s++) {
            float p = __expf(ev[s] - mx);
            sum += p;
            w[node][j] = p;  // identical-value write from both waves: benign
        }
    }
#pragma unroll
    for (int o = 32; o >= 1; o >>= 1) sum += __shfl_xor(sum, o);
    float inv = 1.f / sum;

    const float* hb = h1 + (size_t)b * NN * 128 + half * 64;
    float acc = 0.f;
    int j = 0;
    for (; j + 1 < d; j += 2) {
        float w0 = w[node][j], w1 = w[node][j + 1];
        const float* p0 = hb + (size_t)cl[node][j] * 128;
        const float* p1 = hb + (size_t)cl[node][j + 1] * 128;
        acc += w0 * p0[lane] + w1 * p1[lane];
    }
    if (j < d) acc += w[node][j] * (hb + (size_t)cl[node][j] * 128)[lane];

    float g = 1.f / (1.f + __expf(-acc * inv));
    float st = state[(size_t)bi * 64 + lane];
    if (half == 0)
        rstate[(size_t)bi * 64 + lane] = g * st;
    else
        zbuf[(size_t)bi * 64 + lane] = g;
}

// ---------------- attention layer 2 (F=64), 2 waves/node j-split + GRU ----------------
__global__ __launch_bounds__(256) void attn2_kernel(
    const int* __restrict__ deg, const int* __restrict__ cols,
    const float* __restrict__ h2, const float* __restrict__ s_src,
    const float* __restrict__ s_dst, const float* __restrict__ state,
    const float* __restrict__ zbuf, float* __restrict__ out) {
    int wv = threadIdx.x >> 6;
    int lane = threadIdx.x & 63;
    int node = wv >> 1;
    int half = wv & 1;
    int bi = blockIdx.x * 2 + node;
    int i = bi & (NN - 1);
    int b = bi >> 10;
    int d = deg[i];
    float ssrc = s_src[bi];
    __shared__ float w[2][MAXD];
    __shared__ int cl[2][MAXD];
    __shared__ float part[2][64];

    float ev[3];
    float mx = -1e30f;
    int nslot = 0;
    for (int j = lane; j < d; j += 64, nslot++) {
        int c = cols[(size_t)i * MAXD + j];
        cl[node][j] = c;
        float e = ssrc + s_dst[b * NN + c];
        e = e > 0.f ? e : LALPHA * e;
        ev[nslot] = e;
        mx = fmaxf(mx, e);
    }
#pragma unroll
    for (int o = 32; o >= 1; o >>= 1) mx = fmaxf(mx, __shfl_xor(mx, o));
    float sum = 0.f;
    {
        int s = 0;
        for (int j = lane; j < d; j += 64, s++) {
            float p = __expf(ev[s] - mx);
            sum += p;
            w[node][j] = p;
        }
    }
#pragma unroll
    for (int o = 32; o >= 1; o >>= 1) sum += __shfl_xor(sum, o);
    float inv = 1.f / sum;

    const float* hb = h2 + (size_t)b * NN * 64;
    float acc = 0.f;
    int j = half;
    for (; j + 2 < d; j += 4) {
        float w0 = w[node][j], w1 = w[node][j + 2];
        const float* p0 = hb + (size_t)cl[node][j] * 64;
        const float* p1 = hb + (size_t)cl[node][j + 2] * 64;
        acc += w0 * p0[lane] + w1 * p1[lane];
    }
    for (; j < d; j += 2) acc += w[node][j] * (hb + (size_t)cl[node][j] * 64)[lane];

    if (half == 1) part[node][lane] = acc;
    __syncthreads();
    if (half == 0) {
        acc += part[node][lane];
        float ht = tanhf(acc * inv);
        float z = zbuf[(size_t)bi * 64 + lane];
        float st = state[(size_t)bi * 64 + lane];
        out[(size_t)bi * 64 + lane] = z * st + (1.f - z) * ht;
    }
}

extern "C" void kernel_launch(void* const* d_in, const int* in_sizes, int n_in,
                              void* d_out, int out_size, void* d_ws, size_t ws_size,
                              hipStream_t stream) {
    const float* X     = (const float*)d_in[0];
    const float* state = (const float*)d_in[1];
    const float* adj   = (const float*)d_in[2];
    const float* W1    = (const float*)d_in[3];
    const float* a1    = (const float*)d_in[4];
    const float* W2    = (const float*)d_in[5];
    const float* a2    = (const float*)d_in[6];
    float* out = (float*)d_out;

    char* ws = (char*)d_ws;
    size_t off = 0;
    auto alloc = [&](size_t bytes) -> void* {
        void* p = ws + off;
        off = (off + bytes + 255) & ~(size_t)255;
        return p;
    };
    int*   deg    = (int*)alloc(NN * sizeof(int));
    int*   cols   = (int*)alloc((size_t)NN * MAXD * sizeof(int));
    float* h1     = (float*)alloc((size_t)BB * NN * 128 * sizeof(float));
    float* ssrc1  = (float*)alloc((size_t)BB * NN * sizeof(float));
    float* sdst1  = (float*)alloc((size_t)BB * NN * sizeof(float));
    float* rstate = (float*)alloc((size_t)BB * NN * 64 * sizeof(float));
    float* zbuf   = (float*)alloc((size_t)BB * NN * 64 * sizeof(float));
    float* h2     = (float*)alloc((size_t)BB * NN * 64 * sizeof(float));
    float* ssrc2  = (float*)alloc((size_t)BB * NN * sizeof(float));
    float* sdst2  = (float*)alloc((size_t)BB * NN * sizeof(float));

    const int M = BB * NN;  // 16384

    build_csr<<<NN, 256, 0, stream>>>(adj, deg, cols);
    gemm_score<128, 32><<<M / 32, 256, 0, stream>>>(X, state, W1, a1, h1, ssrc1, sdst1);
    attn1_kernel<<<M / 2, 256, 0, stream>>>(deg, cols, h1, ssrc1, sdst1, state, rstate, zbuf);
    gemm_score<64, 64><<<M / 64, 256, 0, stream>>>(X, rstate, W2, a2, h2, ssrc2, sdst2);
    attn2_kernel<<<M / 2, 256, 0, stream>>>(deg, cols, h2, ssrc2, sdst2, state, zbuf, out);
}

// Round 4
// 146.860 us; speedup vs baseline: 1.0906x; 1.0906x over previous
//
#include <hip/hip_runtime.h>

#define BB 16
#define NN 1024
#define LALPHA 0.2f
#define MAXD 192

// ---------------- CSR build from dense adjacency ----------------
__global__ void build_csr(const float* __restrict__ adj, int* __restrict__ deg,
                          int* __restrict__ cols) {
    __shared__ int cnt;
    int i = blockIdx.x;
    if (threadIdx.x == 0) cnt = 0;
    __syncthreads();
    for (int j = threadIdx.x; j < NN; j += blockDim.x) {
        if (adj[(size_t)i * NN + j] > 0.0f) {
            int p = atomicAdd(&cnt, 1);
            if (p < MAXD) cols[(size_t)i * MAXD + p] = j;
        }
    }
    __syncthreads();
    if (threadIdx.x == 0) deg[i] = cnt < MAXD ? cnt : MAXD;
}

// ---------------- fused GEMM + attention-score epilogue (unchanged from R2) ----------------
template <int FOUT, int RB>
__global__ void gemm_score(const float* __restrict__ A0, const float* __restrict__ A1,
                           const float* __restrict__ W, const float* __restrict__ avec,
                           float* __restrict__ h, float* __restrict__ s_src,
                           float* __restrict__ s_dst) {
    constexpr int TFN = FOUT / 4;
    constexpr int NT = (RB / 4) * TFN;
    __shared__ float xs[RB][132];
    int t = threadIdx.x;
    int tf = t % TFN, tr = t / TFN;
    int f0 = tf * 4, r0 = tr * 4;
    int base = blockIdx.x * RB;

    for (int idx = t; idx < RB * 32; idx += NT) {
        int r = idx >> 5, c = (idx & 31) * 4;
        float4 v = (c < 64) ? *(const float4*)(A0 + (size_t)(base + r) * 64 + c)
                            : *(const float4*)(A1 + (size_t)(base + r) * 64 + (c - 64));
        xs[r][c] = v.x; xs[r][c + 1] = v.y; xs[r][c + 2] = v.z; xs[r][c + 3] = v.w;
    }
    __syncthreads();

    float acc[4][4] = {};
    for (int k = 0; k < 128; k += 4) {
        float4 xv[4], wv[4];
#pragma unroll
        for (int i = 0; i < 4; i++) xv[i] = *(const float4*)&xs[r0 + i][k];
#pragma unroll
        for (int i = 0; i < 4; i++) wv[i] = *(const float4*)(W + (size_t)(k + i) * FOUT + f0);
#pragma unroll
        for (int i = 0; i < 4; i++) {
            float xr[4] = {xv[i].x, xv[i].y, xv[i].z, xv[i].w};
#pragma unroll
            for (int kk = 0; kk < 4; kk++) {
                acc[i][0] += xr[kk] * wv[kk].x;
                acc[i][1] += xr[kk] * wv[kk].y;
                acc[i][2] += xr[kk] * wv[kk].z;
                acc[i][3] += xr[kk] * wv[kk].w;
            }
        }
    }

    float a_s[4], a_d[4];
#pragma unroll
    for (int i = 0; i < 4; i++) {
        a_s[i] = avec[f0 + i];
        a_d[i] = avec[FOUT + f0 + i];
    }
#pragma unroll
    for (int i = 0; i < 4; i++) {
        int m = base + r0 + i;
        *(float4*)(h + (size_t)m * FOUT + f0) =
            make_float4(acc[i][0], acc[i][1], acc[i][2], acc[i][3]);
        float ps = acc[i][0] * a_s[0] + acc[i][1] * a_s[1] + acc[i][2] * a_s[2] + acc[i][3] * a_s[3];
        float pd = acc[i][0] * a_d[0] + acc[i][1] * a_d[1] + acc[i][2] * a_d[2] + acc[i][3] * a_d[3];
#pragma unroll
        for (int o = TFN / 2; o >= 1; o >>= 1) {
            ps += __shfl_xor(ps, o);
            pd += __shfl_xor(pd, o);
        }
        if (tf == 0) {
            s_src[m] = ps;
            s_dst[m] = pd;
        }
    }
}

// ---------------- attention layer 1 (F=128): 1 wave/node, float2 row loads ----------------
// Lane L accumulates features (2L, 2L+1). One dwordx2 instr loads a full 512B row.
__global__ __launch_bounds__(64) void attn1_kernel(
    const int* __restrict__ deg, const int* __restrict__ cols,
    const float* __restrict__ h1, const float* __restrict__ s_src,
    const float* __restrict__ s_dst, const float* __restrict__ state,
    float* __restrict__ rstate, float* __restrict__ zbuf) {
    int bi = blockIdx.x;
    int i = bi & (NN - 1);
    int b = bi >> 10;
    int lane = threadIdx.x;
    int d = deg[i];
    float ssrc = s_src[bi];
    __shared__ float w[MAXD + 4];
    __shared__ int cl[MAXD + 4];

    float ev[3];
    float mx = -1e30f;
    int s = 0;
    for (int j = lane; j < d; j += 64, s++) {
        int c = cols[(size_t)i * MAXD + j];
        cl[j] = c;
        float e = ssrc + s_dst[b * NN + c];
        e = e > 0.f ? e : LALPHA * e;
        ev[s] = e;
        mx = fmaxf(mx, e);
    }
#pragma unroll
    for (int o = 32; o >= 1; o >>= 1) mx = fmaxf(mx, __shfl_xor(mx, o));
    float sum = 0.f;
    s = 0;
    for (int j = lane; j < d; j += 64, s++) {
        float p = __expf(ev[s] - mx);
        w[j] = p;
        sum += p;
    }
#pragma unroll
    for (int o = 32; o >= 1; o >>= 1) sum += __shfl_xor(sum, o);
    if (lane < 4) {  // zero-pad to multiple of 4
        w[d + lane] = 0.f;
        cl[d + lane] = 0;
    }
    __syncthreads();
    float inv = 1.f / sum;

    const float* hb = h1 + (size_t)b * NN * 128 + lane * 2;
    int de4 = (d + 3) & ~3;
    float ax = 0.f, ay = 0.f;
    for (int j = 0; j < de4; j += 4) {
        float2 r0 = *(const float2*)(hb + (size_t)cl[j] * 128);
        float2 r1 = *(const float2*)(hb + (size_t)cl[j + 1] * 128);
        float2 r2 = *(const float2*)(hb + (size_t)cl[j + 2] * 128);
        float2 r3 = *(const float2*)(hb + (size_t)cl[j + 3] * 128);
        float w0 = w[j], w1 = w[j + 1], w2 = w[j + 2], w3 = w[j + 3];
        ax += w0 * r0.x + w1 * r1.x + w2 * r2.x + w3 * r3.x;
        ay += w0 * r0.y + w1 * r1.y + w2 * r2.y + w3 * r3.y;
    }
    float gx = 1.f / (1.f + __expf(-ax * inv));
    float gy = 1.f / (1.f + __expf(-ay * inv));
    if (lane < 32) {  // features 0..63 -> r gate
        float2 st = *(const float2*)(state + (size_t)bi * 64 + lane * 2);
        *(float2*)(rstate + (size_t)bi * 64 + lane * 2) = make_float2(gx * st.x, gy * st.y);
    } else {  // features 64..127 -> z gate
        int l2 = lane - 32;
        *(float2*)(zbuf + (size_t)bi * 64 + l2 * 2) = make_float2(gx, gy);
    }
}

// ---------------- attention layer 2 (F=64): lane-halves cover 2 neighbors/instr ----------------
__global__ __launch_bounds__(64) void attn2_kernel(
    const int* __restrict__ deg, const int* __restrict__ cols,
    const float* __restrict__ h2, const float* __restrict__ s_src,
    const float* __restrict__ s_dst, const float* __restrict__ state,
    const float* __restrict__ zbuf, float* __restrict__ out) {
    int bi = blockIdx.x;
    int i = bi & (NN - 1);
    int b = bi >> 10;
    int lane = threadIdx.x;
    int half = lane >> 5;   // 0: even neighbor, 1: odd neighbor
    int fl = lane & 31;     // feature pair index
    int d = deg[i];
    float ssrc = s_src[bi];
    __shared__ float w[MAXD + 4];
    __shared__ int cl[MAXD + 4];

    float ev[3];
    float mx = -1e30f;
    int s = 0;
    for (int j = lane; j < d; j += 64, s++) {
        int c = cols[(size_t)i * MAXD + j];
        cl[j] = c;
        float e = ssrc + s_dst[b * NN + c];
        e = e > 0.f ? e : LALPHA * e;
        ev[s] = e;
        mx = fmaxf(mx, e);
    }
#pragma unroll
    for (int o = 32; o >= 1; o >>= 1) mx = fmaxf(mx, __shfl_xor(mx, o));
    float sum = 0.f;
    s = 0;
    for (int j = lane; j < d; j += 64, s++) {
        float p = __expf(ev[s] - mx);
        w[j] = p;
        sum += p;
    }
#pragma unroll
    for (int o = 32; o >= 1; o >>= 1) sum += __shfl_xor(sum, o);
    if (lane < 4) {
        w[d + lane] = 0.f;
        cl[d + lane] = 0;
    }
    __syncthreads();
    float inv = 1.f / sum;

    const float* hb = h2 + (size_t)b * NN * 64 + fl * 2;
    int de4 = (d + 3) & ~3;
    float ax = 0.f, ay = 0.f;
    for (int j = 0; j < de4; j += 4) {
        int i0 = j + half, i1 = j + 2 + half;
        float2 r0 = *(const float2*)(hb + (size_t)cl[i0] * 64);
        float2 r1 = *(const float2*)(hb + (size_t)cl[i1] * 64);
        float w0 = w[i0], w1 = w[i1];
        ax += w0 * r0.x + w1 * r1.x;
        ay += w0 * r0.y + w1 * r1.y;
    }
    // combine neighbor-halves: lane L and L+32 hold same feature pair
    ax += __shfl_xor(ax, 32);
    ay += __shfl_xor(ay, 32);
    if (lane < 32) {
        float hx = tanhf(ax * inv);
        float hy = tanhf(ay * inv);
        float2 z2 = *(const float2*)(zbuf + (size_t)bi * 64 + lane * 2);
        float2 st = *(const float2*)(state + (size_t)bi * 64 + lane * 2);
        *(float2*)(out + (size_t)bi * 64 + lane * 2) =
            make_float2(z2.x * st.x + (1.f - z2.x) * hx,
                        z2.y * st.y + (1.f - z2.y) * hy);
    }
}

extern "C" void kernel_launch(void* const* d_in, const int* in_sizes, int n_in,
                              void* d_out, int out_size, void* d_ws, size_t ws_size,
                              hipStream_t stream) {
    const float* X     = (const float*)d_in[0];
    const float* state = (const float*)d_in[1];
    const float* adj   = (const float*)d_in[2];
    const float* W1    = (const float*)d_in[3];
    const float* a1    = (const float*)d_in[4];
    const float* W2    = (const float*)d_in[5];
    const float* a2    = (const float*)d_in[6];
    float* out = (float*)d_out;

    char* ws = (char*)d_ws;
    size_t off = 0;
    auto alloc = [&](size_t bytes) -> void* {
        void* p = ws + off;
        off = (off + bytes + 255) & ~(size_t)255;
        return p;
    };
    int*   deg    = (int*)alloc(NN * sizeof(int));
    int*   cols   = (int*)alloc((size_t)NN * MAXD * sizeof(int));
    float* h1     = (float*)alloc((size_t)BB * NN * 128 * sizeof(float));
    float* ssrc1  = (float*)alloc((size_t)BB * NN * sizeof(float));
    float* sdst1  = (float*)alloc((size_t)BB * NN * sizeof(float));
    float* rstate = (float*)alloc((size_t)BB * NN * 64 * sizeof(float));
    float* zbuf   = (float*)alloc((size_t)BB * NN * 64 * sizeof(float));
    float* h2     = (float*)alloc((size_t)BB * NN * 64 * sizeof(float));
    float* ssrc2  = (float*)alloc((size_t)BB * NN * sizeof(float));
    float* sdst2  = (float*)alloc((size_t)BB * NN * sizeof(float));

    const int M = BB * NN;  // 16384

    build_csr<<<NN, 256, 0, stream>>>(adj, deg, cols);
    gemm_score<128, 32><<<M / 32, 256, 0, stream>>>(X, state, W1, a1, h1, ssrc1, sdst1);
    attn1_kernel<<<M, 64, 0, stream>>>(deg, cols, h1, ssrc1, sdst1, state, rstate, zbuf);
    gemm_score<64, 64><<<M / 64, 256, 0, stream>>>(X, rstate, W2, a2, h2, ssrc2, sdst2);
    attn2_kernel<<<M, 64, 0, stream>>>(deg, cols, h2, ssrc2, sdst2, state, zbuf, out);
}